// Round 1
// baseline (168.993 us; speedup 1.0000x reference)
//
#include <hip/hip_runtime.h>
#include <hip/hip_cooperative_groups.h>

namespace cg = cooperative_groups;

#define B_    16
#define CIN   64
#define COUT  128
#define H_    32
#define W_    32
#define HP    34            // halo-padded spatial dim
#define XCH   136           // 16B chunks per padded qx row = 2*2*34
#define NBLK  512           // (b,y) grid; 2 blocks/CU -> all co-resident

typedef __attribute__((ext_vector_type(4)))  int int4v;    // 16 int8 = 4 VGPRs
typedef __attribute__((ext_vector_type(16))) int int16v;   // 32x32 i8 MFMA C/D

// ---------------------------------------------------------------------------
// Single fused cooperative kernel:
//   Phase 1: per-block max|x|, max|w| -> bmx[512], bmw[512]
//   grid.sync()
//   Phase 2: fold partials to global scales (in-register), quantize exactly
//            like the reference (IEEE div by max/127, rintf, clip +-127),
//            pack qx (halo-padded, MFMA lane order) and qw.
//   grid.sync()
//   Phase 3: conv as 32x32x32 INT8 MFMA (exact: |q|<=127, i32 accum), scaled
//            epilogue with the scales still in registers.
// Rationale: the 3-kernel pipeline was launch/gap-bound (device work ~7 us,
// measured 68.7 us). One dispatch + 2 grid syncs removes 2 kernel boundaries.
// ---------------------------------------------------------------------------
__global__ __launch_bounds__(256, 2) void fused_conv_kernel(
    const float* __restrict__ x, const float* __restrict__ w,
    const float* __restrict__ bias,
    float* __restrict__ bmx, float* __restrict__ bmw,
    char* __restrict__ qx,   // s8 [16][34][2][2][34][16]
    char* __restrict__ qw,   // s8 [9][2][2][128][16]
    float* __restrict__ out) {
  cg::grid_group grid = cg::this_grid();

  const int t    = threadIdx.x;
  const int bb   = blockIdx.x;
  const int lane = t & 63;
  const int wid  = t >> 6;

  __shared__ __align__(16) char lds[W_ * 80];  // [x][cin], pad 64->80
  __shared__ float smx[4], smw[4];

  // ---------------- Phase 1: block-partial maxabs ----------------
  {
    const float4* __restrict__ x4 = (const float4*)x;
    const float4* __restrict__ w4 = (const float4*)w;
    const int g = bb * 256 + t;                // [0, 131072)
    float mx, mw = 0.0f;
    float4 v0 = x4[g];
    float4 v1 = x4[g + 131072];                // 262144 float4 total
    mx = fmaxf(fmaxf(fmaxf(fabsf(v0.x), fabsf(v0.y)),
                     fmaxf(fabsf(v0.z), fabsf(v0.w))),
               fmaxf(fmaxf(fabsf(v1.x), fabsf(v1.y)),
                     fmaxf(fabsf(v1.z), fabsf(v1.w))));
    if (g < COUT * CIN * 9 / 4) {              // 18432 float4 of w
      float4 v = w4[g];
      mw = fmaxf(fmaxf(fabsf(v.x), fabsf(v.y)),
                 fmaxf(fabsf(v.z), fabsf(v.w)));
    }
#pragma unroll
    for (int off = 32; off > 0; off >>= 1) {
      mx = fmaxf(mx, __shfl_down(mx, off, 64));
      mw = fmaxf(mw, __shfl_down(mw, off, 64));
    }
    if (lane == 0) { smx[wid] = mx; smw[wid] = mw; }
    __syncthreads();
    if (t == 0) {
#pragma unroll
      for (int i = 1; i < 4; ++i) { mx = fmaxf(mx, smx[i]); mw = fmaxf(mw, smw[i]); }
      bmx[bb] = mx;
      bmw[bb] = mw;
    }
  }

  grid.sync();

  // ---------------- fold 512 partials -> global scales (all lanes) --------
  float gmx = 0.0f, gmw = 0.0f;
#pragma unroll
  for (int i = 0; i < 8; ++i) {
    gmx = fmaxf(gmx, bmx[lane + 64 * i]);
    gmw = fmaxf(gmw, bmw[lane + 64 * i]);
  }
#pragma unroll
  for (int off = 32; off > 0; off >>= 1) {
    gmx = fmaxf(gmx, __shfl_down(gmx, off, 64));
    gmw = fmaxf(gmw, __shfl_down(gmw, off, 64));
  }
  gmx = __shfl(gmx, 0, 64);
  gmw = __shfl(gmw, 0, 64);
  const float sx = gmx / 127.0f;
  const float sw = gmw / 127.0f;

  // ---------------- Phase 2: quantize + pack ----------------
  const int b = bb >> 5, y = bb & 31;
  {
#pragma unroll
    for (int k = 0; k < 8; ++k) {
      const int u = t + k * 256;               // [0, 2048)
      const int cin = u >> 5, xx = u & 31;     // coalesced along x
      float q = rintf(x[((b * CIN + cin) * H_ + y) * W_ + xx] / sx);
      q = fminf(fmaxf(q, -127.0f), 127.0f);
      lds[xx * 80 + cin] = (char)(int)q;
    }
    // weights: 512 blocks x 144 elements = 73728
    if (t < 144) {
      const int i = bb * 144 + t;
      float q = rintf(w[i] / sw);
      q = fminf(fmaxf(q, -127.0f), 127.0f);
      // i = ((o*64 + c)*3 + kh)*3 + kw
      const int kw = i % 3; int j = i / 3;
      const int kh = j % 3; j /= 3;
      const int c = j & 63; const int o = j >> 6;
      const int sidx = kh * 3 + kw;
      const int c32 = c >> 5, kb = (c >> 4) & 1, e = c & 15;
      qw[(size_t)(((sidx * 2 + c32) * 2 + kb) * 128 + o) * 16 + e] = (char)(int)q;
    }
    __syncthreads();
    // write 136 16-B chunks: c = (c32*2+kb)*34 + xs
    char* row = qx + (size_t)(b * HP + y + 1) * (XCH * 16);
    if (t < XCH) {
      const int c32 = t / 68;
      const int r   = t - c32 * 68;
      const int kb  = r / 34;
      const int xs  = r - kb * 34;
      uint4 v; v.x = v.y = v.z = v.w = 0;
      if (xs >= 1 && xs <= 32)
        v = *(const uint4*)(&lds[(xs - 1) * 80 + c32 * 32 + kb * 16]);
      *(uint4*)(row + t * 16) = v;
    }
    // zero halo rows (32 of them) folded into blocks 0..31
    if (bb < 32 && t < XCH) {
      const int b2 = bb >> 1, yy = (bb & 1) ? 33 : 0;
      char* hrow = qx + (size_t)(b2 * HP + yy) * (XCH * 16);
      uint4 z; z.x = z.y = z.z = z.w = 0;
      *(uint4*)(hrow + t * 16) = z;
    }
  }

  grid.sync();

  // ---------------- Phase 3: INT8 MFMA conv ----------------
  // Wave = 32 pixels (row y) x 32 couts. A frag: A[m=lane&31][k=(lane>>5)*16+j]
  // B: B[k][n=lane&31]. D: col=lane&31 (pixel x),
  // row=(reg&3)+8*(reg>>2)+4*(lane>>5) (cout). Two acc chains, exact int sum.
  {
    const int col = lane & 31;                 // pixel x / cout row
    const int kb  = lane >> 5;                 // k-half within 32
    const int co0 = wid * 32;

    int16v acc0 = (int16v)0, acc1 = (int16v)0;

    // qx byte offsets: ((((b*34 + y+kh)*2 + c32)*2 + kb)*34 + col+kw)*16
    const char* __restrict__ xp =
        qx + ((size_t)(b * HP + y) * 4 + kb) * 544 + col * 16;
    // qw byte offsets: (((s*2 + c32)*2 + kb)*128 + co0+col)*16
    const char* __restrict__ wp = qw + (kb * 128 + co0 + col) * 16;

#pragma unroll
    for (int kh = 0; kh < 3; ++kh) {
      const char* __restrict__ xr = xp + (size_t)kh * (4 * 544);
#pragma unroll
      for (int kw = 0; kw < 3; ++kw) {
        const int s = kh * 3 + kw;
#pragma unroll
        for (int c32 = 0; c32 < 2; ++c32) {
          int4v a  = *(const int4v*)(wp + (s * 2 + c32) * 4096);
          int4v bf = *(const int4v*)(xr + c32 * 1088 + kw * 16);
          if (((s * 2 + c32) & 1) == 0)
            acc0 = __builtin_amdgcn_mfma_i32_32x32x32_i8(a, bf, acc0, 0, 0, 0);
          else
            acc1 = __builtin_amdgcn_mfma_i32_32x32x32_i8(a, bf, acc1, 0, 0, 0);
        }
      }
    }

    const float sc = sx * sw;
#pragma unroll
    for (int r = 0; r < 16; ++r) {
      const int row  = (r & 3) + 8 * (r >> 2) + 4 * kb;
      const int cout = co0 + row;
      out[((b * COUT + cout) << 10) + y * W_ + col] =
          sc * (float)(acc0[r] + acc1[r]) + bias[cout];
    }
  }
}

// ---------------------------------------------------------------------------
extern "C" void kernel_launch(void* const* d_in, const int* in_sizes, int n_in,
                              void* d_out, int out_size, void* d_ws, size_t ws_size,
                              hipStream_t stream) {
  const float* x    = (const float*)d_in[0];
  const float* w    = (const float*)d_in[1];
  const float* bias = (const float*)d_in[2];
  float* out = (float*)d_out;

  // ws: bmx[512] | bmw[512] | qx s8 [16][34][136][16] (1.19 MB) | qw s8 (73.7 KB)
  float* bmx = (float*)d_ws;
  float* bmw = bmx + 512;
  char* qx = (char*)d_ws + 4096;
  char* qw = qx + (size_t)B_ * HP * XCH * 16;

  void* args[] = {(void*)&x, (void*)&w, (void*)&bias, (void*)&bmx,
                  (void*)&bmw, (void*)&qx, (void*)&qw, (void*)&out};
  hipLaunchCooperativeKernel((const void*)fused_conv_kernel,
                             dim3(NBLK), dim3(256), args, 0, stream);
}